// Round 1
// baseline (1427.055 us; speedup 1.0000x reference)
//
#include <hip/hip_runtime.h>

// ---------------------------------------------------------------------------
// GINENet: 2x GINEConv(aggr) + MLP chain, all fp32.
// N=50000, E=800000, D=128.
// ---------------------------------------------------------------------------

__global__ void copy_f4(const float4* __restrict__ src, float4* __restrict__ dst, int n4) {
    int i = blockIdx.x * blockDim.x + threadIdx.x;
    if (i < n4) dst[i] = src[i];
}

// One edge handled by 128 threads (thread d = feature dim d). Block = 2 edges.
// msg = relu(x[src] + ea*ew + eb); atomicAdd into agg[dst]. Zero messages skipped.
__global__ void edge_aggr(const float* __restrict__ x, const float* __restrict__ ea,
                          const int* __restrict__ ei, const float* __restrict__ ew,
                          const float* __restrict__ eb, float* __restrict__ agg, int E) {
    int edge = blockIdx.x * 2 + (threadIdx.x >> 7);
    int d = threadIdx.x & 127;
    if (edge >= E) return;
    int s = ei[edge];       // src = edge_index[0][edge]
    int t = ei[E + edge];   // dst = edge_index[1][edge]
    float e = fmaf(ea[edge], ew[d], eb[d]);
    float m = x[(long)s * 128 + d] + e;
    if (m > 0.f) atomicAdd(&agg[(long)t * 128 + d], m);
}

// out[r][o] = relu( sum_k in[r][k] * W[o][k] + bias[o] )
// in = concat(in0 [DIN0], in1 [DIN1]) per row. 64 rows/block, K tiled by 32.
template <int DIN0, int DIN1, int DOUT, int TM, int TN>
__global__ __launch_bounds__((DOUT / TN) * (64 / TM))
void mm_relu(const float* __restrict__ in0, const float* __restrict__ in1,
             const float* __restrict__ W, const float* __restrict__ bias,
             float* __restrict__ out, int n) {
    constexpr int DIN = DIN0 + DIN1;
    constexpr int BK = 32;
    constexpr int LDW = BK + 1;          // pad to break bank conflicts
    constexpr int CG = DOUT / TN;        // col groups
    constexpr int RG = 64 / TM;          // row groups
    constexpr int NT = CG * RG;
    __shared__ float wS[DOUT * LDW];
    __shared__ float yS[64 * LDW];
    int tid = threadIdx.x;
    int row0 = blockIdx.x * 64;
    int rowg = tid % RG;                 // lanes vary fastest in rows -> W reads broadcast-ish
    int colg = tid / RG;

    float acc[TM][TN];
#pragma unroll
    for (int i = 0; i < TM; ++i)
#pragma unroll
        for (int j = 0; j < TN; ++j) acc[i][j] = 0.f;

    for (int k0 = 0; k0 < DIN; k0 += BK) {
        for (int i = tid; i < DOUT * BK; i += NT) {
            int o = i / BK, k = i % BK;
            wS[o * LDW + k] = W[o * DIN + k0 + k];
        }
        for (int i = tid; i < 64 * BK; i += NT) {
            int r = i / BK, k = i % BK;
            int gr = row0 + r, gk = k0 + k;
            float v = 0.f;
            if (gr < n) {
                if (DIN1 == 0 || gk < DIN0)
                    v = in0[(long)gr * DIN0 + gk];
                else
                    v = in1[(long)gr * DIN1 + (gk - DIN0)];
            }
            yS[r * LDW + k] = v;
        }
        __syncthreads();
#pragma unroll
        for (int k = 0; k < BK; ++k) {
            float yv[TM], wv[TN];
#pragma unroll
            for (int i = 0; i < TM; ++i) yv[i] = yS[(rowg * TM + i) * LDW + k];
#pragma unroll
            for (int j = 0; j < TN; ++j) wv[j] = wS[(colg * TN + j) * LDW + k];
#pragma unroll
            for (int i = 0; i < TM; ++i)
#pragma unroll
                for (int j = 0; j < TN; ++j) acc[i][j] = fmaf(yv[i], wv[j], acc[i][j]);
        }
        __syncthreads();
    }
#pragma unroll
    for (int i = 0; i < TM; ++i) {
        int gr = row0 + rowg * TM + i;
        if (gr >= n) continue;
#pragma unroll
        for (int j = 0; j < TN; ++j) {
            int c = colg * TN + j;
            out[(long)gr * DOUT + c] = fmaxf(acc[i][j] + bias[c], 0.f);
        }
    }
}

// Column-wise sum and sum-of-squares. blockDim = DOUT, each block reduces a row
// range privately then one atomicAdd per column. sums layout: [sum[DOUT], sumsq[DOUT]]
template <int DOUT>
__global__ void col_stats(const float* __restrict__ t, int n, float* __restrict__ sums) {
    int col = threadIdx.x;
    int rows_per = (n + gridDim.x - 1) / gridDim.x;
    int r0 = blockIdx.x * rows_per;
    int r1 = min(n, r0 + rows_per);
    float s = 0.f, ss = 0.f;
    for (int r = r0; r < r1; ++r) {
        float v = t[(long)r * DOUT + col];
        s += v;
        ss += v * v;
    }
    atomicAdd(&sums[col], s);
    atomicAdd(&sums[DOUT + col], ss);
}

template <int DOUT>
__global__ void bn_finalize(const float* __restrict__ sums, const float* __restrict__ g,
                            const float* __restrict__ beta, float* __restrict__ scsh,
                            float inv_n) {
    int c = threadIdx.x;
    float mu = sums[c] * inv_n;
    float var = sums[DOUT + c] * inv_n - mu * mu;
    float sc = g[c] * rsqrtf(var + 1e-5f);
    scsh[c] = sc;
    scsh[DOUT + c] = fmaf(-mu, sc, beta[c]);
}

template <int DOUT>
__global__ void bn_apply(const float* __restrict__ t, const float* __restrict__ scsh,
                         float* __restrict__ out, long total) {
    long idx = (long)blockIdx.x * blockDim.x + threadIdx.x;
    if (idx < total) {
        int c = (int)(idx % DOUT);
        out[idx] = fmaf(t[idx], scsh[c], scsh[DOUT + c]);
    }
}

extern "C" void kernel_launch(void* const* d_in, const int* in_sizes, int n_in,
                              void* d_out, int out_size, void* d_ws, size_t ws_size,
                              hipStream_t stream) {
    const float* x    = (const float*)d_in[0];
    const int*   ei   = (const int*)d_in[1];
    const float* ea   = (const float*)d_in[2];
    const float* elw  = (const float*)d_in[3];
    const float* elb  = (const float*)d_in[4];
    const float* c1w  = (const float*)d_in[5];
    const float* c1b  = (const float*)d_in[6];
    const float* c1g  = (const float*)d_in[7];
    const float* c1bt = (const float*)d_in[8];
    const float* c2w  = (const float*)d_in[9];
    const float* c2b  = (const float*)d_in[10];
    const float* c2g  = (const float*)d_in[11];
    const float* c2bt = (const float*)d_in[12];
    const float* l1w  = (const float*)d_in[13];
    const float* l1b  = (const float*)d_in[14];
    const float* l1g  = (const float*)d_in[15];
    const float* l1bt = (const float*)d_in[16];
    const float* m1w  = (const float*)d_in[17];
    const float* m1b  = (const float*)d_in[18];
    const float* m1g  = (const float*)d_in[19];
    const float* m1bt = (const float*)d_in[20];
    const float* m2w  = (const float*)d_in[21];
    const float* m2b  = (const float*)d_in[22];
    const float* m2g  = (const float*)d_in[23];
    const float* m2bt = (const float*)d_in[24];

    const int n = in_sizes[0] / 128;   // 50000
    const int E = in_sizes[2];         // 800000
    const float inv_n = 1.0f / (float)n;

    float* ws = (float*)d_ws;
    float* bufY  = ws;                          // [n,128] aggregation target / t3 / t5
    float* bufT  = bufY + (size_t)n * 128;      // [n,128] t1 / t2->x2 / t4->h4
    float* bufX1 = bufT + (size_t)n * 128;      // [n,128] x1 (live until lin1)
    float* stats = bufX1 + (size_t)n * 128;     // 5 * 256 floats
    float* scsh  = stats + 1280;                // 5 * 256 floats

    hipMemsetAsync(stats, 0, 1280 * sizeof(float), stream);

    const int n4 = n * 32;  // n*128/4 float4 elements
    const int cp_grid = (n4 + 255) / 256;
    const int eg_grid = (E + 1) / 2;
    const int mm_grid = (n + 63) / 64;

    // ---- conv1: y1 = x + sum relu(x[src]+e) ; t1 = relu(y1@c1_w.T+b); x1 = BN(t1)
    copy_f4<<<cp_grid, 256, 0, stream>>>((const float4*)x, (float4*)bufY, n4);
    edge_aggr<<<eg_grid, 256, 0, stream>>>(x, ea, ei, elw, elb, bufY, E);
    mm_relu<128, 0, 128, 4, 8><<<mm_grid, 256, 0, stream>>>(bufY, nullptr, c1w, c1b, bufT, n);
    col_stats<128><<<256, 128, 0, stream>>>(bufT, n, stats + 0);
    bn_finalize<128><<<1, 128, 0, stream>>>(stats + 0, c1g, c1bt, scsh + 0, inv_n);
    bn_apply<128><<<(int)(((long)n * 128 + 255) / 256), 256, 0, stream>>>(bufT, scsh + 0, bufX1, (long)n * 128);

    // ---- conv2: y2 = x1 + sum relu(x1[src]+e) ; t2 = relu(y2@c2_w.T+b); x2 = BN(t2) in-place
    copy_f4<<<cp_grid, 256, 0, stream>>>((const float4*)bufX1, (float4*)bufY, n4);
    edge_aggr<<<eg_grid, 256, 0, stream>>>(bufX1, ea, ei, elw, elb, bufY, E);
    mm_relu<128, 0, 64, 4, 4><<<mm_grid, 256, 0, stream>>>(bufY, nullptr, c2w, c2b, bufT, n);
    col_stats<64><<<256, 64, 0, stream>>>(bufT, n, stats + 256);
    bn_finalize<64><<<1, 64, 0, stream>>>(stats + 256, c2g, c2bt, scsh + 256, inv_n);
    bn_apply<64><<<(int)(((long)n * 64 + 255) / 256), 256, 0, stream>>>(bufT, scsh + 256, bufT, (long)n * 64);

    // ---- lin1: t3 = relu([x1|x2]@l1_w.T+b) -> bufY ; h3 = BN in-place
    mm_relu<128, 64, 96, 4, 6><<<mm_grid, 256, 0, stream>>>(bufX1, bufT, l1w, l1b, bufY, n);
    col_stats<96><<<256, 96, 0, stream>>>(bufY, n, stats + 512);
    bn_finalize<96><<<1, 96, 0, stream>>>(stats + 512, l1g, l1bt, scsh + 512, inv_n);
    bn_apply<96><<<(int)(((long)n * 96 + 255) / 256), 256, 0, stream>>>(bufY, scsh + 512, bufY, (long)n * 96);

    // ---- mlp1 layer1: t4 = relu(h3@m1_w.T+b) -> bufT ; h4 = BN in-place
    mm_relu<96, 0, 96, 4, 6><<<mm_grid, 256, 0, stream>>>(bufY, nullptr, m1w, m1b, bufT, n);
    col_stats<96><<<256, 96, 0, stream>>>(bufT, n, stats + 768);
    bn_finalize<96><<<1, 96, 0, stream>>>(stats + 768, m1g, m1bt, scsh + 768, inv_n);
    bn_apply<96><<<(int)(((long)n * 96 + 255) / 256), 256, 0, stream>>>(bufT, scsh + 768, bufT, (long)n * 96);

    // ---- mlp1 layer2: t5 = relu(h4@m2_w.T+b) -> bufY ; out = BN -> d_out
    mm_relu<96, 0, 8, 1, 1><<<mm_grid, 512, 0, stream>>>(bufT, nullptr, m2w, m2b, bufY, n);
    col_stats<8><<<256, 8, 0, stream>>>(bufY, n, stats + 1024);
    bn_finalize<8><<<1, 8, 0, stream>>>(stats + 1024, m2g, m2bt, scsh + 1024, inv_n);
    bn_apply<8><<<(int)(((long)n * 8 + 255) / 256), 256, 0, stream>>>(bufY, scsh + 1024, (float*)d_out, (long)n * 8);
}

// Round 2
// 753.473 us; speedup vs baseline: 1.8940x; 1.8940x over previous
//
#include <hip/hip_runtime.h>

// ---------------------------------------------------------------------------
// GINENet, fp32. N=50000, E=800000, D=128.
// Round 2: CSR (sort-by-dst) gather-side aggregation replaces atomic scatter;
// col_stats fused into matmul epilogue; BN-affine fused into matmul input.
// ---------------------------------------------------------------------------

// ============================ CSR build =====================================
__global__ void histo(const int* __restrict__ ei, int* __restrict__ cnt, int E) {
    int i = blockIdx.x * blockDim.x + threadIdx.x;
    if (i < E) atomicAdd(&cnt[ei[E + i]], 1);
}

// 1024 elements per block (256 thr x 4), block-local exclusive scan + block total
__global__ void scan_block(const int* __restrict__ cnt, int* __restrict__ excl,
                           int* __restrict__ part, int n) {
    __shared__ int s[256];
    int t = threadIdx.x;
    int base = blockIdx.x * 1024 + t * 4;
    int v0 = (base + 0 < n) ? cnt[base + 0] : 0;
    int v1 = (base + 1 < n) ? cnt[base + 1] : 0;
    int v2 = (base + 2 < n) ? cnt[base + 2] : 0;
    int v3 = (base + 3 < n) ? cnt[base + 3] : 0;
    int tsum = v0 + v1 + v2 + v3;
    s[t] = tsum;
    __syncthreads();
    for (int off = 1; off < 256; off <<= 1) {
        int x = (t >= off) ? s[t - off] : 0;
        __syncthreads();
        s[t] += x;
        __syncthreads();
    }
    int tbase = s[t] - tsum;
    if (base + 0 < n) excl[base + 0] = tbase;
    if (base + 1 < n) excl[base + 1] = tbase + v0;
    if (base + 2 < n) excl[base + 2] = tbase + v0 + v1;
    if (base + 3 < n) excl[base + 3] = tbase + v0 + v1 + v2;
    if (t == 255) part[blockIdx.x] = s[255];
}

__global__ void scan_carry(int* part, int nb) {
    int run = 0;
    for (int i = 0; i < nb; ++i) { int v = part[i]; part[i] = run; run += v; }
}

__global__ void scan_add(int* __restrict__ excl, const int* __restrict__ part, int n) {
    int i = blockIdx.x * blockDim.x + threadIdx.x;
    if (i < n) excl[i] += part[i >> 10];
}

__global__ void scatter_csr(const int* __restrict__ ei, const int* __restrict__ start,
                            int* __restrict__ fill, int* __restrict__ srcS,
                            int* __restrict__ eidS, int E) {
    int i = blockIdx.x * blockDim.x + threadIdx.x;
    if (i < E) {
        int dnode = ei[E + i];
        int pos = start[dnode] + atomicAdd(&fill[dnode], 1);
        srcS[pos] = ei[i];
        eidS[pos] = i;
    }
}

// =================== gather-side GINE aggregation ===========================
// One block (128 thr) per node v: agg[v] = x[v] + sum_{j in in(v)} relu(x[src_j] + e_j)
__global__ __launch_bounds__(128)
void agg_csr(const float* __restrict__ x, const float* __restrict__ ea,
             const float* __restrict__ ew, const float* __restrict__ eb,
             const int* __restrict__ srcS, const int* __restrict__ eidS,
             const int* __restrict__ start, const int* __restrict__ cnt,
             float* __restrict__ agg) {
    int v = blockIdx.x;
    int d = threadIdx.x;
    int s0 = start[v];
    int deg = cnt[v];
    float wd = ew[d], bd = eb[d];
    float acc = 0.f;
    int j = 0;
    for (; j + 1 < deg; j += 2) {
        int sA = srcS[s0 + j],     sB = srcS[s0 + j + 1];
        int eA = eidS[s0 + j],     eB = eidS[s0 + j + 1];
        float mA = fmaf(ea[eA], wd, bd) + x[(long)sA * 128 + d];
        float mB = fmaf(ea[eB], wd, bd) + x[(long)sB * 128 + d];
        acc += fmaxf(mA, 0.f) + fmaxf(mB, 0.f);
    }
    if (j < deg) {
        int sA = srcS[s0 + j];
        int eA = eidS[s0 + j];
        float mA = fmaf(ea[eA], wd, bd) + x[(long)sA * 128 + d];
        acc += fmaxf(mA, 0.f);
    }
    agg[(long)v * 128 + d] = x[(long)v * 128 + d] + acc;
}

// ======================= matmul + relu + fused stats ========================
// out[r][o] = relu( sum_k inBN[r][k] * W[o][k] + bias[o] )
// in = concat(in0 [DIN0] (affine scshA), in1 [DIN1] (affine scshB)).
// Epilogue accumulates per-column sum / sumsq into stats via LDS + atomics.
template <int DIN0, int DIN1, int DOUT, int TM, int TN>
__global__ __launch_bounds__((DOUT / TN) * (64 / TM))
void mm_relu(const float* __restrict__ in0, const float* __restrict__ in1,
             const float* __restrict__ scshA, const float* __restrict__ scshB,
             const float* __restrict__ W, const float* __restrict__ bias,
             float* __restrict__ out, float* __restrict__ stats, int n) {
    constexpr int DIN = DIN0 + DIN1;
    constexpr int BK = 32;
    constexpr int LDW = BK + 1;
    constexpr int CG = DOUT / TN;
    constexpr int RG = 64 / TM;
    constexpr int NT = CG * RG;
    __shared__ float wS[DOUT * LDW];
    __shared__ float yS[64 * LDW];
    int tid = threadIdx.x;
    int row0 = blockIdx.x * 64;
    int rowg = tid % RG;
    int colg = tid / RG;

    float acc[TM][TN];
#pragma unroll
    for (int i = 0; i < TM; ++i)
#pragma unroll
        for (int j = 0; j < TN; ++j) acc[i][j] = 0.f;

    for (int k0 = 0; k0 < DIN; k0 += BK) {
        for (int i = tid; i < DOUT * BK; i += NT) {
            int o = i / BK, k = i % BK;
            wS[o * LDW + k] = W[o * DIN + k0 + k];
        }
        for (int i = tid; i < 64 * BK; i += NT) {
            int r = i / BK, k = i % BK;
            int gr = row0 + r, gk = k0 + k;
            float v = 0.f;
            if (gr < n) {
                if (DIN1 == 0 || gk < DIN0) {
                    v = in0[(long)gr * DIN0 + gk];
                    if (scshA) v = fmaf(v, scshA[gk], scshA[DIN0 + gk]);
                } else {
                    int c = gk - DIN0;
                    v = in1[(long)gr * DIN1 + c];
                    if (scshB) v = fmaf(v, scshB[c], scshB[DIN1 + c]);
                }
            }
            yS[r * LDW + k] = v;
        }
        __syncthreads();
#pragma unroll
        for (int k = 0; k < BK; ++k) {
            float yv[TM], wv[TN];
#pragma unroll
            for (int i = 0; i < TM; ++i) yv[i] = yS[(rowg * TM + i) * LDW + k];
#pragma unroll
            for (int j = 0; j < TN; ++j) wv[j] = wS[(colg * TN + j) * LDW + k];
#pragma unroll
            for (int i = 0; i < TM; ++i)
#pragma unroll
                for (int j = 0; j < TN; ++j) acc[i][j] = fmaf(yv[i], wv[j], acc[i][j]);
        }
        __syncthreads();
    }

    float s_loc[TN], ss_loc[TN];
#pragma unroll
    for (int j = 0; j < TN; ++j) { s_loc[j] = 0.f; ss_loc[j] = 0.f; }
#pragma unroll
    for (int i = 0; i < TM; ++i) {
        int gr = row0 + rowg * TM + i;
        if (gr >= n) continue;
#pragma unroll
        for (int j = 0; j < TN; ++j) {
            int c = colg * TN + j;
            float v = fmaxf(acc[i][j] + bias[c], 0.f);
            out[(long)gr * DOUT + c] = v;
            s_loc[j] += v;
            ss_loc[j] += v * v;
        }
    }
    // per-block column reduction in LDS (reuse wS), then one global atomic/col
    float* cs = wS;
    for (int i = tid; i < 2 * DOUT; i += NT) cs[i] = 0.f;
    __syncthreads();
#pragma unroll
    for (int j = 0; j < TN; ++j) {
        int c = colg * TN + j;
        atomicAdd(&cs[c], s_loc[j]);
        atomicAdd(&cs[DOUT + c], ss_loc[j]);
    }
    __syncthreads();
    for (int i = tid; i < 2 * DOUT; i += NT) atomicAdd(&stats[i], cs[i]);
}

// ============================ BN helpers ====================================
template <int DOUT>
__global__ void bn_finalize(const float* __restrict__ sums, const float* __restrict__ g,
                            const float* __restrict__ beta, float* __restrict__ scsh,
                            float inv_n) {
    int c = threadIdx.x;
    float mu = sums[c] * inv_n;
    float var = sums[DOUT + c] * inv_n - mu * mu;
    float sc = g[c] * rsqrtf(var + 1e-5f);
    scsh[c] = sc;
    scsh[DOUT + c] = fmaf(-mu, sc, beta[c]);
}

template <int DOUT>
__global__ void bn_apply(const float* __restrict__ t, const float* __restrict__ scsh,
                         float* __restrict__ out, long total) {
    long idx = (long)blockIdx.x * blockDim.x + threadIdx.x;
    if (idx < total) {
        int c = (int)(idx % DOUT);
        out[idx] = fmaf(t[idx], scsh[c], scsh[DOUT + c]);
    }
}

// ============================ driver ========================================
extern "C" void kernel_launch(void* const* d_in, const int* in_sizes, int n_in,
                              void* d_out, int out_size, void* d_ws, size_t ws_size,
                              hipStream_t stream) {
    const float* x    = (const float*)d_in[0];
    const int*   ei   = (const int*)d_in[1];
    const float* ea   = (const float*)d_in[2];
    const float* elw  = (const float*)d_in[3];
    const float* elb  = (const float*)d_in[4];
    const float* c1w  = (const float*)d_in[5];
    const float* c1b  = (const float*)d_in[6];
    const float* c1g  = (const float*)d_in[7];
    const float* c1bt = (const float*)d_in[8];
    const float* c2w  = (const float*)d_in[9];
    const float* c2b  = (const float*)d_in[10];
    const float* c2g  = (const float*)d_in[11];
    const float* c2bt = (const float*)d_in[12];
    const float* l1w  = (const float*)d_in[13];
    const float* l1b  = (const float*)d_in[14];
    const float* l1g  = (const float*)d_in[15];
    const float* l1bt = (const float*)d_in[16];
    const float* m1w  = (const float*)d_in[17];
    const float* m1b  = (const float*)d_in[18];
    const float* m1g  = (const float*)d_in[19];
    const float* m1bt = (const float*)d_in[20];
    const float* m2w  = (const float*)d_in[21];
    const float* m2b  = (const float*)d_in[22];
    const float* m2g  = (const float*)d_in[23];
    const float* m2bt = (const float*)d_in[24];

    const int n = in_sizes[0] / 128;   // 50000
    const int E = in_sizes[2];         // 800000
    const float inv_n = 1.0f / (float)n;

    float* ws    = (float*)d_ws;
    float* bufY  = ws;                          // [n,128]
    float* bufT  = bufY + (size_t)n * 128;      // [n,128]
    float* bufX1 = bufT + (size_t)n * 128;      // [n,128]
    float* stats = bufX1 + (size_t)n * 128;     // 5 * 256
    float* scsh  = stats + 1280;                // 5 * 256
    int* cnt    = (int*)(scsh + 1280);          // [n]
    int* fill   = cnt + n;                      // [n]
    int* startA = fill + n;                     // [n]
    int* part   = startA + n;                   // [64]
    int* srcS   = part + 64;                    // [E]
    int* eidS   = srcS + E;                     // [E]

    hipMemsetAsync(stats, 0, 1280 * sizeof(float), stream);
    hipMemsetAsync(cnt, 0, (size_t)2 * n * sizeof(int), stream);  // cnt + fill

    const int eg_grid = (E + 255) / 256;
    const int mm_grid = (n + 63) / 64;
    const int nb = (n + 1023) / 1024;

    // ---- CSR build (dst-sorted edge list), reused by both convs
    histo<<<eg_grid, 256, 0, stream>>>(ei, cnt, E);
    scan_block<<<nb, 256, 0, stream>>>(cnt, startA, part, n);
    scan_carry<<<1, 1, 0, stream>>>(part, nb);
    scan_add<<<(n + 255) / 256, 256, 0, stream>>>(startA, part, n);
    scatter_csr<<<eg_grid, 256, 0, stream>>>(ei, startA, fill, srcS, eidS, E);

    // ---- conv1
    agg_csr<<<n, 128, 0, stream>>>(x, ea, elw, elb, srcS, eidS, startA, cnt, bufY);
    mm_relu<128, 0, 128, 4, 8><<<mm_grid, 256, 0, stream>>>(
        bufY, nullptr, nullptr, nullptr, c1w, c1b, bufT, stats + 0, n);
    bn_finalize<128><<<1, 128, 0, stream>>>(stats + 0, c1g, c1bt, scsh + 0, inv_n);
    bn_apply<128><<<(int)(((long)n * 128 + 255) / 256), 256, 0, stream>>>(
        bufT, scsh + 0, bufX1, (long)n * 128);

    // ---- conv2 (t2 stays pre-BN; its affine is fused into lin1's input read)
    agg_csr<<<n, 128, 0, stream>>>(bufX1, ea, elw, elb, srcS, eidS, startA, cnt, bufY);
    mm_relu<128, 0, 64, 4, 4><<<mm_grid, 256, 0, stream>>>(
        bufY, nullptr, nullptr, nullptr, c2w, c2b, bufT, stats + 256, n);
    bn_finalize<64><<<1, 64, 0, stream>>>(stats + 256, c2g, c2bt, scsh + 256, inv_n);

    // ---- lin1: in0 = x1 (already BN'd), in1 = t2 with fused scsh1 -> t3 (pre-BN)
    mm_relu<128, 64, 96, 4, 6><<<mm_grid, 256, 0, stream>>>(
        bufX1, bufT, nullptr, scsh + 256, l1w, l1b, bufY, stats + 512, n);
    bn_finalize<96><<<1, 96, 0, stream>>>(stats + 512, l1g, l1bt, scsh + 512, inv_n);

    // ---- mlp1 layer1: in0 = t3 with fused scsh2 -> t4 (pre-BN)
    mm_relu<96, 0, 96, 4, 6><<<mm_grid, 256, 0, stream>>>(
        bufY, nullptr, scsh + 512, nullptr, m1w, m1b, bufT, stats + 768, n);
    bn_finalize<96><<<1, 96, 0, stream>>>(stats + 768, m1g, m1bt, scsh + 768, inv_n);

    // ---- mlp1 layer2: in0 = t4 with fused scsh3 -> t5; final BN -> d_out
    mm_relu<96, 0, 8, 1, 1><<<mm_grid, 512, 0, stream>>>(
        bufT, nullptr, scsh + 768, nullptr, m2w, m2b, bufY, stats + 1024, n);
    bn_finalize<8><<<1, 8, 0, stream>>>(stats + 1024, m2g, m2bt, scsh + 1024, inv_n);
    bn_apply<8><<<(int)(((long)n * 8 + 255) / 256), 256, 0, stream>>>(
        bufY, scsh + 1024, (float*)d_out, (long)n * 8);
}

// Round 3
// 629.323 us; speedup vs baseline: 2.2676x; 1.1973x over previous
//
#include <hip/hip_runtime.h>

// ---------------------------------------------------------------------------
// GINENet, fp32. N=50000, E=800000, D=128.
// Round 3: rebuilt matmul (f4 staging, conflict-free LDS b64 reads, strided
// row tiles); BN-affine of x1 fused into agg gather; int2 CSR payload.
// ---------------------------------------------------------------------------

// ============================ CSR build =====================================
__global__ void histo(const int* __restrict__ ei, int* __restrict__ cnt, int E) {
    int i = blockIdx.x * blockDim.x + threadIdx.x;
    if (i < E) atomicAdd(&cnt[ei[E + i]], 1);
}

__global__ void scan_block(const int* __restrict__ cnt, int* __restrict__ excl,
                           int* __restrict__ part, int n) {
    __shared__ int s[256];
    int t = threadIdx.x;
    int base = blockIdx.x * 1024 + t * 4;
    int v0 = (base + 0 < n) ? cnt[base + 0] : 0;
    int v1 = (base + 1 < n) ? cnt[base + 1] : 0;
    int v2 = (base + 2 < n) ? cnt[base + 2] : 0;
    int v3 = (base + 3 < n) ? cnt[base + 3] : 0;
    int tsum = v0 + v1 + v2 + v3;
    s[t] = tsum;
    __syncthreads();
    for (int off = 1; off < 256; off <<= 1) {
        int x = (t >= off) ? s[t - off] : 0;
        __syncthreads();
        s[t] += x;
        __syncthreads();
    }
    int tbase = s[t] - tsum;
    if (base + 0 < n) excl[base + 0] = tbase;
    if (base + 1 < n) excl[base + 1] = tbase + v0;
    if (base + 2 < n) excl[base + 2] = tbase + v0 + v1;
    if (base + 3 < n) excl[base + 3] = tbase + v0 + v1 + v2;
    if (t == 255) part[blockIdx.x] = s[255];
}

__global__ void scan_carry(int* part, int nb) {
    int run = 0;
    for (int i = 0; i < nb; ++i) { int v = part[i]; part[i] = run; run += v; }
}

__global__ void scan_add(int* __restrict__ excl, const int* __restrict__ part, int n) {
    int i = blockIdx.x * blockDim.x + threadIdx.x;
    if (i < n) excl[i] += part[i >> 10];
}

__global__ void scatter_csr(const int* __restrict__ ei, const int* __restrict__ start,
                            int* __restrict__ fill, int2* __restrict__ srcEid, int E) {
    int i = blockIdx.x * blockDim.x + threadIdx.x;
    if (i < E) {
        int dnode = ei[E + i];
        int pos = start[dnode] + atomicAdd(&fill[dnode], 1);
        srcEid[pos] = make_int2(ei[i], i);
    }
}

// =================== gather-side GINE aggregation ===========================
// One block (128 thr) per node v:
//   agg[v] = xbn[v] + sum_{j in in(v)} relu(xbn[src_j] + ea_j*ew + eb)
// where xbn = x*sc + sh (scsh nullable -> identity).
__global__ __launch_bounds__(128)
void agg_csr(const float* __restrict__ x, const float* __restrict__ ea,
             const float* __restrict__ ew, const float* __restrict__ eb,
             const int2* __restrict__ srcEid, const int* __restrict__ start,
             const int* __restrict__ cnt, const float* __restrict__ scsh,
             float* __restrict__ agg) {
    int v = blockIdx.x;
    int d = threadIdx.x;
    int s0 = start[v];
    int deg = cnt[v];
    float wd = ew[d], bd = eb[d];
    float sc = scsh ? scsh[d] : 1.f;
    float sh = scsh ? scsh[128 + d] : 0.f;
    float acc = 0.f;
    int j = 0;
    for (; j + 3 < deg; j += 4) {
        int2 p0 = srcEid[s0 + j + 0];
        int2 p1 = srcEid[s0 + j + 1];
        int2 p2 = srcEid[s0 + j + 2];
        int2 p3 = srcEid[s0 + j + 3];
        float g0 = x[(long)p0.x * 128 + d];
        float g1 = x[(long)p1.x * 128 + d];
        float g2 = x[(long)p2.x * 128 + d];
        float g3 = x[(long)p3.x * 128 + d];
        float e0 = fmaf(ea[p0.y], wd, bd);
        float e1 = fmaf(ea[p1.y], wd, bd);
        float e2 = fmaf(ea[p2.y], wd, bd);
        float e3 = fmaf(ea[p3.y], wd, bd);
        acc += fmaxf(fmaf(g0, sc, sh) + e0, 0.f);
        acc += fmaxf(fmaf(g1, sc, sh) + e1, 0.f);
        acc += fmaxf(fmaf(g2, sc, sh) + e2, 0.f);
        acc += fmaxf(fmaf(g3, sc, sh) + e3, 0.f);
    }
    for (; j < deg; ++j) {
        int2 p = srcEid[s0 + j];
        float g = x[(long)p.x * 128 + d];
        acc += fmaxf(fmaf(g, sc, sh) + fmaf(ea[p.y], wd, bd), 0.f);
    }
    float self = fmaf(x[(long)v * 128 + d], sc, sh);
    agg[(long)v * 128 + d] = self + acc;
}

// ======================= matmul + relu + fused stats ========================
// out[r][o] = relu( sum_k inBN[r][k] * W[o][k] + bias[o] )
// in = concat(in0 [DIN0] (affine scshA), in1 [DIN1] (affine scshB)).
// Thread tile: TM rows (strided by RG) x TN cols. LDS leading dim 34
// (lane stride == 1 row == 34 words == 2 banks -> conflict-free b64 reads).
template <int DIN0, int DIN1, int DOUT, int BM, int TM, int TN>
__global__ __launch_bounds__((BM / TM) * (DOUT / TN))
void mm_relu(const float* __restrict__ in0, const float* __restrict__ in1,
             const float* __restrict__ scshA, const float* __restrict__ scshB,
             const float* __restrict__ W, const float* __restrict__ bias,
             float* __restrict__ out, float* __restrict__ stats, int n) {
    constexpr int DIN = DIN0 + DIN1;
    constexpr int BK = 32;
    constexpr int LDK = BK + 2;          // 34: stride ≡ 2 mod 32
    constexpr int RG = BM / TM;
    constexpr int CG = DOUT / TN;
    constexpr int NT = RG * CG;
    constexpr int KF4 = BK / 4;          // f4 chunks per row per tile
    __shared__ float yS[BM * LDK];
    __shared__ float wS[DOUT * LDK];
    int tid = threadIdx.x;
    int row0 = blockIdx.x * BM;
    int rowg = tid % RG;
    int colg = tid / RG;

    float acc[TM][TN];
#pragma unroll
    for (int i = 0; i < TM; ++i)
#pragma unroll
        for (int j = 0; j < TN; ++j) acc[i][j] = 0.f;

    for (int k0 = 0; k0 < DIN; k0 += BK) {
        // stage W tile (f4 loads)
        for (int idx = tid; idx < DOUT * KF4; idx += NT) {
            int o = idx / KF4, k4 = idx % KF4;
            float4 v = *(const float4*)(W + (long)o * DIN + k0 + k4 * 4);
            float* p = &wS[o * LDK + k4 * 4];
            p[0] = v.x; p[1] = v.y; p[2] = v.z; p[3] = v.w;
        }
        // stage y tile (f4 loads + optional affine)
        for (int idx = tid; idx < BM * KF4; idx += NT) {
            int r = idx / KF4, k4 = idx % KF4;
            int gr = row0 + r, gk = k0 + k4 * 4;
            float4 v = make_float4(0.f, 0.f, 0.f, 0.f);
            if (gr < n) {
                if (DIN1 == 0 || gk < DIN0) {
                    v = *(const float4*)(in0 + (long)gr * DIN0 + gk);
                    if (scshA) {
                        v.x = fmaf(v.x, scshA[gk + 0], scshA[DIN0 + gk + 0]);
                        v.y = fmaf(v.y, scshA[gk + 1], scshA[DIN0 + gk + 1]);
                        v.z = fmaf(v.z, scshA[gk + 2], scshA[DIN0 + gk + 2]);
                        v.w = fmaf(v.w, scshA[gk + 3], scshA[DIN0 + gk + 3]);
                    }
                } else {
                    int c = gk - DIN0;
                    v = *(const float4*)(in1 + (long)gr * DIN1 + c);
                    if (scshB) {
                        v.x = fmaf(v.x, scshB[c + 0], scshB[DIN1 + c + 0]);
                        v.y = fmaf(v.y, scshB[c + 1], scshB[DIN1 + c + 1]);
                        v.z = fmaf(v.z, scshB[c + 2], scshB[DIN1 + c + 2]);
                        v.w = fmaf(v.w, scshB[c + 3], scshB[DIN1 + c + 3]);
                    }
                }
            }
            float* p = &yS[r * LDK + k4 * 4];
            p[0] = v.x; p[1] = v.y; p[2] = v.z; p[3] = v.w;
        }
        __syncthreads();
#pragma unroll
        for (int k = 0; k < BK; k += 2) {
            float2 wv[TN], yv[TM];
#pragma unroll
            for (int j = 0; j < TN; ++j)
                wv[j] = *(const float2*)&wS[(colg * TN + j) * LDK + k];
#pragma unroll
            for (int i = 0; i < TM; ++i)
                yv[i] = *(const float2*)&yS[(rowg + RG * i) * LDK + k];
#pragma unroll
            for (int i = 0; i < TM; ++i)
#pragma unroll
                for (int j = 0; j < TN; ++j) {
                    acc[i][j] = fmaf(yv[i].x, wv[j].x, acc[i][j]);
                    acc[i][j] = fmaf(yv[i].y, wv[j].y, acc[i][j]);
                }
        }
        __syncthreads();
    }

    // epilogue: bias + relu + store + per-column stats
    float s_loc[TN], ss_loc[TN];
#pragma unroll
    for (int j = 0; j < TN; ++j) { s_loc[j] = 0.f; ss_loc[j] = 0.f; }
#pragma unroll
    for (int i = 0; i < TM; ++i) {
        int gr = row0 + rowg + RG * i;
        if (gr >= n) continue;
#pragma unroll
        for (int j = 0; j < TN; ++j) {
            int c = colg * TN + j;
            float v = fmaxf(acc[i][j] + bias[c], 0.f);
            out[(long)gr * DOUT + c] = v;
            s_loc[j] += v;
            ss_loc[j] += v * v;
        }
    }
    float* cs = wS;   // reuse (all k-loop LDS reads are behind the final barrier)
    for (int i = tid; i < 2 * DOUT; i += NT) cs[i] = 0.f;
    __syncthreads();
#pragma unroll
    for (int j = 0; j < TN; ++j) {
        int c = colg * TN + j;
        atomicAdd(&cs[c], s_loc[j]);
        atomicAdd(&cs[DOUT + c], ss_loc[j]);
    }
    __syncthreads();
    for (int i = tid; i < 2 * DOUT; i += NT) atomicAdd(&stats[i], cs[i]);
}

// ============================ BN helpers ====================================
template <int DOUT>
__global__ void bn_finalize(const float* __restrict__ sums, const float* __restrict__ g,
                            const float* __restrict__ beta, float* __restrict__ scsh,
                            float inv_n) {
    int c = threadIdx.x;
    float mu = sums[c] * inv_n;
    float var = sums[DOUT + c] * inv_n - mu * mu;
    float sc = g[c] * rsqrtf(var + 1e-5f);
    scsh[c] = sc;
    scsh[DOUT + c] = fmaf(-mu, sc, beta[c]);
}

template <int DOUT>
__global__ void bn_apply(const float* __restrict__ t, const float* __restrict__ scsh,
                         float* __restrict__ out, long total) {
    long idx = (long)blockIdx.x * blockDim.x + threadIdx.x;
    if (idx < total) {
        int c = (int)(idx % DOUT);
        out[idx] = fmaf(t[idx], scsh[c], scsh[DOUT + c]);
    }
}

// ============================ driver ========================================
extern "C" void kernel_launch(void* const* d_in, const int* in_sizes, int n_in,
                              void* d_out, int out_size, void* d_ws, size_t ws_size,
                              hipStream_t stream) {
    const float* x    = (const float*)d_in[0];
    const int*   ei   = (const int*)d_in[1];
    const float* ea   = (const float*)d_in[2];
    const float* elw  = (const float*)d_in[3];
    const float* elb  = (const float*)d_in[4];
    const float* c1w  = (const float*)d_in[5];
    const float* c1b  = (const float*)d_in[6];
    const float* c1g  = (const float*)d_in[7];
    const float* c1bt = (const float*)d_in[8];
    const float* c2w  = (const float*)d_in[9];
    const float* c2b  = (const float*)d_in[10];
    const float* c2g  = (const float*)d_in[11];
    const float* c2bt = (const float*)d_in[12];
    const float* l1w  = (const float*)d_in[13];
    const float* l1b  = (const float*)d_in[14];
    const float* l1g  = (const float*)d_in[15];
    const float* l1bt = (const float*)d_in[16];
    const float* m1w  = (const float*)d_in[17];
    const float* m1b  = (const float*)d_in[18];
    const float* m1g  = (const float*)d_in[19];
    const float* m1bt = (const float*)d_in[20];
    const float* m2w  = (const float*)d_in[21];
    const float* m2b  = (const float*)d_in[22];
    const float* m2g  = (const float*)d_in[23];
    const float* m2bt = (const float*)d_in[24];

    const int n = in_sizes[0] / 128;   // 50000
    const int E = in_sizes[2];         // 800000
    const float inv_n = 1.0f / (float)n;

    float* ws    = (float*)d_ws;
    float* B1    = ws;                          // [n,128] agg scratch / t3
    float* B2    = B1 + (size_t)n * 128;        // [n,128] t1 / t4
    float* B3    = B2 + (size_t)n * 128;        // [n,64]  t2 / t5
    float* stats = B3 + (size_t)n * 64;         // 5 * 256
    float* scsh  = stats + 1280;                // 5 * 256
    int* cnt    = (int*)(scsh + 1280);          // [n]
    int* fill   = cnt + n;                      // [n]
    int* startA = fill + n;                     // [n]
    int* part   = startA + n;                   // [64]
    int2* srcEid = (int2*)(part + 64);          // [E]

    hipMemsetAsync(stats, 0, 1280 * sizeof(float), stream);
    hipMemsetAsync(cnt, 0, (size_t)2 * n * sizeof(int), stream);  // cnt + fill

    const int eg_grid = (E + 255) / 256;
    const int mm_grid = (n + 63) / 64;
    const int nb = (n + 1023) / 1024;

    // ---- CSR build (dst-sorted edge list), reused by both convs
    histo<<<eg_grid, 256, 0, stream>>>(ei, cnt, E);
    scan_block<<<nb, 256, 0, stream>>>(cnt, startA, part, n);
    scan_carry<<<1, 1, 0, stream>>>(part, nb);
    scan_add<<<(n + 255) / 256, 256, 0, stream>>>(startA, part, n);
    scatter_csr<<<eg_grid, 256, 0, stream>>>(ei, startA, fill, srcEid, E);

    // ---- conv1: agg(x) -> B1 ; t1 = relu(B1@c1w.T+b) -> B2 (pre-BN) ; scsh0
    agg_csr<<<n, 128, 0, stream>>>(x, ea, elw, elb, srcEid, startA, cnt, nullptr, B1);
    mm_relu<128, 0, 128, 64, 4, 8><<<mm_grid, 256, 0, stream>>>(
        B1, nullptr, nullptr, nullptr, c1w, c1b, B2, stats + 0, n);
    bn_finalize<128><<<1, 128, 0, stream>>>(stats + 0, c1g, c1bt, scsh + 0, inv_n);

    // ---- conv2: agg(BN(t1)) -> B1 ; t2 -> B3 (pre-BN) ; scsh1
    agg_csr<<<n, 128, 0, stream>>>(B2, ea, elw, elb, srcEid, startA, cnt, scsh + 0, B1);
    mm_relu<128, 0, 64, 64, 4, 4><<<mm_grid, 256, 0, stream>>>(
        B1, nullptr, nullptr, nullptr, c2w, c2b, B3, stats + 256, n);
    bn_finalize<64><<<1, 64, 0, stream>>>(stats + 256, c2g, c2bt, scsh + 256, inv_n);

    // ---- lin1: in0 = t1 (affine scsh0), in1 = t2 (affine scsh1) -> t3 -> B1
    mm_relu<128, 64, 96, 64, 4, 6><<<mm_grid, 256, 0, stream>>>(
        B2, B3, scsh + 0, scsh + 256, l1w, l1b, B1, stats + 512, n);
    bn_finalize<96><<<1, 96, 0, stream>>>(stats + 512, l1g, l1bt, scsh + 512, inv_n);

    // ---- mlp1 layer1: in0 = t3 (affine scsh2) -> t4 -> B2
    mm_relu<96, 0, 96, 64, 4, 6><<<mm_grid, 256, 0, stream>>>(
        B1, nullptr, scsh + 512, nullptr, m1w, m1b, B2, stats + 768, n);
    bn_finalize<96><<<1, 96, 0, stream>>>(stats + 768, m1g, m1bt, scsh + 768, inv_n);

    // ---- mlp1 layer2: in0 = t4 (affine scsh3) -> t5 -> B3 ; final BN -> d_out
    mm_relu<96, 0, 8, 64, 2, 1><<<mm_grid, 256, 0, stream>>>(
        B2, nullptr, scsh + 768, nullptr, m2w, m2b, B3, stats + 1024, n);
    bn_finalize<8><<<1, 8, 0, stream>>>(stats + 1024, m2g, m2bt, scsh + 1024, inv_n);
    bn_apply<8><<<(int)(((long)n * 8 + 255) / 256), 256, 0, stream>>>(
        B3, scsh + 1024, (float*)d_out, (long)n * 8);
}

// Round 4
// 501.608 us; speedup vs baseline: 2.8450x; 1.2546x over previous
//
#include <hip/hip_runtime.h>

// ---------------------------------------------------------------------------
// GINENet, N=50000, E=800000, D=128.
// Round 4: MFMA bf16 matmuls (BN affine folded into weights), bf16 hidden
// tensors, CSR gather aggregation with edge-attr folded into payload.
// ---------------------------------------------------------------------------

typedef unsigned short u16;
typedef unsigned int u32;

using bfrag = __attribute__((ext_vector_type(8))) short;  // 8 bf16
using ffrag = __attribute__((ext_vector_type(4))) float;  // 4 fp32 acc

__device__ __forceinline__ u16 f2b(float f) {
    u32 u = __float_as_uint(f);
    return (u16)((u + 0x7FFFu + ((u >> 16) & 1u)) >> 16);   // RNE
}
__device__ __forceinline__ float b2f(u16 h) {
    return __uint_as_float(((u32)h) << 16);
}

// ============================ CSR build =====================================
__global__ void histo(const int* __restrict__ ei, int* __restrict__ cnt, int E) {
    int i = blockIdx.x * blockDim.x + threadIdx.x;
    if (i < E) atomicAdd(&cnt[ei[E + i]], 1);
}

__global__ void scan_block(const int* __restrict__ cnt, int* __restrict__ excl,
                           int* __restrict__ part, int n) {
    __shared__ int s[256];
    int t = threadIdx.x;
    int base = blockIdx.x * 1024 + t * 4;
    int v0 = (base + 0 < n) ? cnt[base + 0] : 0;
    int v1 = (base + 1 < n) ? cnt[base + 1] : 0;
    int v2 = (base + 2 < n) ? cnt[base + 2] : 0;
    int v3 = (base + 3 < n) ? cnt[base + 3] : 0;
    int tsum = v0 + v1 + v2 + v3;
    s[t] = tsum;
    __syncthreads();
    for (int off = 1; off < 256; off <<= 1) {
        int x = (t >= off) ? s[t - off] : 0;
        __syncthreads();
        s[t] += x;
        __syncthreads();
    }
    int tbase = s[t] - tsum;
    if (base + 0 < n) excl[base + 0] = tbase;
    if (base + 1 < n) excl[base + 1] = tbase + v0;
    if (base + 2 < n) excl[base + 2] = tbase + v0 + v1;
    if (base + 3 < n) excl[base + 3] = tbase + v0 + v1 + v2;
    if (t == 255) part[blockIdx.x] = s[255];
}

__global__ void scan_carry(int* part, int nb) {
    int run = 0;
    for (int i = 0; i < nb; ++i) { int v = part[i]; part[i] = run; run += v; }
}

__global__ void scan_add(int* __restrict__ excl, const int* __restrict__ part, int n) {
    int i = blockIdx.x * blockDim.x + threadIdx.x;
    if (i < n) excl[i] += part[i >> 10];
}

// payload: (src node, edge_attr scalar as bits) — kills the ea indirection later
__global__ void scatter_csr(const int* __restrict__ ei, const float* __restrict__ ea,
                            const int* __restrict__ start, int* __restrict__ fill,
                            int2* __restrict__ srcEa, int E) {
    int i = blockIdx.x * blockDim.x + threadIdx.x;
    if (i < E) {
        int dnode = ei[E + i];
        int pos = start[dnode] + atomicAdd(&fill[dnode], 1);
        srcEa[pos] = make_int2(ei[i], __float_as_int(ea[i]));
    }
}

// ======================== fp32 -> bf16 convert ==============================
__global__ void conv_f2b(const float4* __restrict__ src, uint2* __restrict__ dst, int n4) {
    int i = blockIdx.x * blockDim.x + threadIdx.x;
    if (i < n4) {
        float4 v = src[i];
        uint2 o;
        o.x = (u32)f2b(v.x) | ((u32)f2b(v.y) << 16);
        o.y = (u32)f2b(v.z) | ((u32)f2b(v.w) << 16);
        dst[i] = o;
    }
}

// ==================== weight fold + bf16 convert ============================
// Wb[o][k] = bf16( W[o][k] * sc[k] ),  biasp[o] = bias[o] + sum_k W[o][k]*sh[k]
// scshA covers k in [0,DIN0) (layout [sc|sh]), scshB covers [DIN0,DIN0+DIN1).
// Rows o >= DOUT (pad rows) are zero-filled. One wave per row.
__global__ __launch_bounds__(64)
void fold_w(const float* __restrict__ W, const float* __restrict__ bias,
            const float* __restrict__ scshA, const float* __restrict__ scshB,
            u16* __restrict__ Wb, float* __restrict__ biasp,
            int DIN0, int DIN1, int DOUT) {
    int o = blockIdx.x;
    int DIN = DIN0 + DIN1;
    int lane = threadIdx.x;
    if (o >= DOUT) {
        for (int k = lane; k < DIN; k += 64) Wb[o * DIN + k] = 0;
        if (lane == 0) biasp[o] = 0.f;
        return;
    }
    float part = 0.f;
    for (int k = lane; k < DIN; k += 64) {
        float w = W[o * DIN + k];
        float sc = 1.f, sh = 0.f;
        if (k < DIN0) {
            if (scshA) { sc = scshA[k]; sh = scshA[DIN0 + k]; }
        } else {
            if (scshB) { sc = scshB[k - DIN0]; sh = scshB[DIN1 + (k - DIN0)]; }
        }
        Wb[o * DIN + k] = f2b(w * sc);
        part += w * sh;
    }
    for (int off = 32; off; off >>= 1) part += __shfl_down(part, off);
    if (lane == 0) biasp[o] = bias[o] + part;
}

// =================== gather-side GINE aggregation (bf16) ====================
// One block (128 thr) per node v:
//   agg[v] = xbn[v] + sum_j relu(xbn[src_j] + ea_j*ew + eb),  xbn = x*sc+sh
__global__ __launch_bounds__(128)
void agg_csr(const u16* __restrict__ x, const float* __restrict__ ew,
             const float* __restrict__ eb, const int2* __restrict__ srcEa,
             const int* __restrict__ start, const int* __restrict__ cnt,
             const float* __restrict__ scsh, u16* __restrict__ agg) {
    int v = blockIdx.x;
    int d = threadIdx.x;
    int s0 = start[v];
    int deg = cnt[v];
    float wd = ew[d], bd = eb[d];
    float sc = scsh ? scsh[d] : 1.f;
    float sh = scsh ? scsh[128 + d] : 0.f;
    float acc = 0.f;
    int j = 0;
    for (; j + 3 < deg; j += 4) {
        int2 p0 = srcEa[s0 + j + 0];
        int2 p1 = srcEa[s0 + j + 1];
        int2 p2 = srcEa[s0 + j + 2];
        int2 p3 = srcEa[s0 + j + 3];
        float g0 = b2f(x[(long)p0.x * 128 + d]);
        float g1 = b2f(x[(long)p1.x * 128 + d]);
        float g2 = b2f(x[(long)p2.x * 128 + d]);
        float g3 = b2f(x[(long)p3.x * 128 + d]);
        acc += fmaxf(fmaf(g0, sc, sh) + fmaf(__int_as_float(p0.y), wd, bd), 0.f);
        acc += fmaxf(fmaf(g1, sc, sh) + fmaf(__int_as_float(p1.y), wd, bd), 0.f);
        acc += fmaxf(fmaf(g2, sc, sh) + fmaf(__int_as_float(p2.y), wd, bd), 0.f);
        acc += fmaxf(fmaf(g3, sc, sh) + fmaf(__int_as_float(p3.y), wd, bd), 0.f);
    }
    for (; j < deg; ++j) {
        int2 p = srcEa[s0 + j];
        float g = b2f(x[(long)p.x * 128 + d]);
        acc += fmaxf(fmaf(g, sc, sh) + fmaf(__int_as_float(p.y), wd, bd), 0.f);
    }
    float self = fmaf(b2f(x[(long)v * 128 + d]), sc, sh);
    agg[(long)v * 128 + d] = f2b(self + acc);
}

// ======================= MFMA matmul + relu + stats =========================
// out[r][o] = relu( in[r] . Wb[o] + biasp[o] ),  in = concat(in0, in1) bf16.
// 256 thr = 4 waves; wave w handles rows [w*16, w*16+16) of a 64-row tile.
// LDS row stride DIN+8 bf16 (byte stride ≡ 16 mod 128 -> 2-way = free).
template <int DIN0, int DIN1, int DOUTP, int DOUT>
__global__ __launch_bounds__(256)
void mm_mfma(const u16* __restrict__ in0, const u16* __restrict__ in1,
             const u16* __restrict__ Wb, const float* __restrict__ biasp,
             u16* __restrict__ out, float* __restrict__ stats, int n) {
    constexpr int DIN = DIN0 + DIN1;
    constexpr int DINP = DIN + 8;
    constexpr int BM = 64;
    constexpr int NCF = DOUTP / 16;   // col fragments
    constexpr int NKT = DIN / 32;     // k tiles
    __shared__ u16 yS[BM * DINP];
    __shared__ u16 wS[DOUTP * DINP];
    const int tid = threadIdx.x;
    const int row0 = blockIdx.x * BM;

    // ---- stage W tile (16B chunks, coalesced)
    for (int idx = tid; idx < DOUTP * (DIN / 8); idx += 256) {
        int o = idx / (DIN / 8), c = idx % (DIN / 8);
        uint4 v = *(const uint4*)(Wb + (long)o * DIN + c * 8);
        *(uint4*)&wS[o * DINP + c * 8] = v;
    }
    // ---- stage input rows (in0 part)
    for (int idx = tid; idx < BM * (DIN0 / 8); idx += 256) {
        int r = idx / (DIN0 / 8), c = idx % (DIN0 / 8);
        int gr = row0 + r;
        uint4 v = make_uint4(0, 0, 0, 0);
        if (gr < n) v = *(const uint4*)(in0 + (long)gr * DIN0 + c * 8);
        *(uint4*)&yS[r * DINP + c * 8] = v;
    }
    // ---- stage input rows (in1 part, if concat)
    if (DIN1 > 0) {
        for (int idx = tid; idx < BM * (DIN1 / 8); idx += 256) {
            int r = idx / (DIN1 / 8), c = idx % (DIN1 / 8);
            int gr = row0 + r;
            uint4 v = make_uint4(0, 0, 0, 0);
            if (gr < n) v = *(const uint4*)(in1 + (long)gr * DIN1 + c * 8);
            *(uint4*)&yS[r * DINP + DIN0 + c * 8] = v;
        }
    }
    __syncthreads();

    const int wv = tid >> 6;
    const int lane = tid & 63;
    const int mrow = lane & 15;   // A row in 16-tile / D col
    const int kg = lane >> 4;     // k-group 0..3

    ffrag acc[NCF];
#pragma unroll
    for (int cf = 0; cf < NCF; ++cf) acc[cf] = (ffrag){0.f, 0.f, 0.f, 0.f};

    const u16* yBase = &yS[(wv * 16 + mrow) * DINP + kg * 8];
#pragma unroll
    for (int kt = 0; kt < NKT; ++kt) {
        bfrag a = *(const bfrag*)(yBase + kt * 32);
#pragma unroll
        for (int cf = 0; cf < NCF; ++cf) {
            bfrag b = *(const bfrag*)&wS[(cf * 16 + mrow) * DINP + kt * 32 + kg * 8];
            acc[cf] = __builtin_amdgcn_mfma_f32_16x16x32_bf16(a, b, acc[cf], 0, 0, 0);
        }
    }

    // ---- epilogue: bias + relu + bf16 store + column stats
    __syncthreads();                   // done with k-loop LDS reads
    float* cs = (float*)yS;            // reuse staging LDS for column sums
    for (int i = tid; i < 2 * DOUT; i += 256) cs[i] = 0.f;
    __syncthreads();

    const int col = lane & 15;
#pragma unroll
    for (int cf = 0; cf < NCF; ++cf) {
        int c = cf * 16 + col;
        if (DOUTP != DOUT && c >= DOUT) continue;
        float bv = biasp[c];
        float bsum = 0.f, bss = 0.f;
#pragma unroll
        for (int r = 0; r < 4; ++r) {
            int gr = row0 + wv * 16 + kg * 4 + r;   // D row = (lane>>4)*4 + reg
            if (gr < n) {
                float v = fmaxf(acc[cf][r] + bv, 0.f);
                out[(long)gr * DOUT + c] = f2b(v);
                bsum += v;
                bss += v * v;
            }
        }
        atomicAdd(&cs[c], bsum);
        atomicAdd(&cs[DOUT + c], bss);
    }
    __syncthreads();
    for (int i = tid; i < 2 * DOUT; i += 256) atomicAdd(&stats[i], cs[i]);
}

// ============================ BN helpers ====================================
template <int DOUT>
__global__ void bn_finalize(const float* __restrict__ sums, const float* __restrict__ g,
                            const float* __restrict__ beta, float* __restrict__ scsh,
                            float inv_n) {
    int c = threadIdx.x;
    float mu = sums[c] * inv_n;
    float var = sums[DOUT + c] * inv_n - mu * mu;
    float sc = g[c] * rsqrtf(var + 1e-5f);
    scsh[c] = sc;
    scsh[DOUT + c] = fmaf(-mu, sc, beta[c]);
}

__global__ void bn_apply_out(const u16* __restrict__ t, const float* __restrict__ scsh,
                             float* __restrict__ out, int total) {
    int i = blockIdx.x * blockDim.x + threadIdx.x;
    if (i < total) {
        int c = i & 7;
        out[i] = fmaf(b2f(t[i]), scsh[c], scsh[8 + c]);
    }
}

// ============================ driver ========================================
extern "C" void kernel_launch(void* const* d_in, const int* in_sizes, int n_in,
                              void* d_out, int out_size, void* d_ws, size_t ws_size,
                              hipStream_t stream) {
    const float* x    = (const float*)d_in[0];
    const int*   ei   = (const int*)d_in[1];
    const float* ea   = (const float*)d_in[2];
    const float* elw  = (const float*)d_in[3];
    const float* elb  = (const float*)d_in[4];
    const float* c1w  = (const float*)d_in[5];
    const float* c1b  = (const float*)d_in[6];
    const float* c1g  = (const float*)d_in[7];
    const float* c1bt = (const float*)d_in[8];
    const float* c2w  = (const float*)d_in[9];
    const float* c2b  = (const float*)d_in[10];
    const float* c2g  = (const float*)d_in[11];
    const float* c2bt = (const float*)d_in[12];
    const float* l1w  = (const float*)d_in[13];
    const float* l1b  = (const float*)d_in[14];
    const float* l1g  = (const float*)d_in[15];
    const float* l1bt = (const float*)d_in[16];
    const float* m1w  = (const float*)d_in[17];
    const float* m1b  = (const float*)d_in[18];
    const float* m1g  = (const float*)d_in[19];
    const float* m1bt = (const float*)d_in[20];
    const float* m2w  = (const float*)d_in[21];
    const float* m2b  = (const float*)d_in[22];
    const float* m2g  = (const float*)d_in[23];
    const float* m2bt = (const float*)d_in[24];

    const int n = in_sizes[0] / 128;   // 50000
    const int E = in_sizes[2];         // 800000
    const float inv_n = 1.0f / (float)n;

    char* wp = (char*)d_ws;
    auto alloc = [&](size_t bytes) { char* p = wp; wp += (bytes + 31) & ~(size_t)31; return p; };

    float* stats  = (float*)alloc(1280 * 4);
    float* scsh   = (float*)alloc(1280 * 4);
    float* biasp  = (float*)alloc(5 * 128 * 4);
    int*   cnt    = (int*)alloc((size_t)n * 4);
    int*   fill   = (int*)alloc((size_t)n * 4);     // contiguous after cnt
    int*   startA = (int*)alloc((size_t)n * 4);
    int*   part   = (int*)alloc(64 * 4);
    int2*  srcEa  = (int2*)alloc((size_t)E * 8);
    u16*   xb     = (u16*)alloc((size_t)n * 128 * 2);
    u16*   Ab     = (u16*)alloc((size_t)n * 128 * 2);
    u16*   T1     = (u16*)alloc((size_t)n * 128 * 2);
    u16*   T2     = (u16*)alloc((size_t)n * 64 * 2);
    u16*   T3     = (u16*)alloc((size_t)n * 96 * 2);
    u16*   T4     = (u16*)alloc((size_t)n * 96 * 2);
    u16*   T5     = (u16*)alloc((size_t)n * 8 * 2);
    u16*   Wb1    = (u16*)alloc(128 * 128 * 2);
    u16*   Wb2    = (u16*)alloc(64 * 128 * 2);
    u16*   Wb3    = (u16*)alloc(96 * 192 * 2);
    u16*   Wb4    = (u16*)alloc(96 * 96 * 2);
    u16*   Wb5    = (u16*)alloc(16 * 96 * 2);

    hipMemsetAsync(stats, 0, 1280 * 4, stream);
    hipMemsetAsync(cnt, 0, (size_t)2 * n * 4, stream);   // cnt + fill

    const int eg_grid = (E + 255) / 256;
    const int mm_grid = (n + 63) / 64;
    const int nb = (n + 1023) / 1024;

    // ---- CSR build (dst-sorted, edge attr folded into payload)
    histo<<<eg_grid, 256, 0, stream>>>(ei, cnt, E);
    scan_block<<<nb, 256, 0, stream>>>(cnt, startA, part, n);
    scan_carry<<<1, 1, 0, stream>>>(part, nb);
    scan_add<<<(n + 255) / 256, 256, 0, stream>>>(startA, part, n);
    scatter_csr<<<eg_grid, 256, 0, stream>>>(ei, ea, startA, fill, srcEa, E);

    // ---- input + static weight conversions (independent of BN chain)
    conv_f2b<<<(n * 32 + 255) / 256, 256, 0, stream>>>((const float4*)x, (uint2*)xb, n * 32);
    fold_w<<<128, 64, 0, stream>>>(c1w, c1b, nullptr, nullptr, Wb1, biasp + 0, 128, 0, 128);
    fold_w<<<64, 64, 0, stream>>>(c2w, c2b, nullptr, nullptr, Wb2, biasp + 128, 128, 0, 64);

    // ---- conv1
    agg_csr<<<n, 128, 0, stream>>>(xb, elw, elb, srcEa, startA, cnt, nullptr, Ab);
    mm_mfma<128, 0, 128, 128><<<mm_grid, 256, 0, stream>>>(Ab, nullptr, Wb1, biasp + 0, T1, stats + 0, n);
    bn_finalize<128><<<1, 128, 0, stream>>>(stats + 0, c1g, c1bt, scsh + 0, inv_n);

    // ---- conv2 (BN(t1) applied inside the gather)
    agg_csr<<<n, 128, 0, stream>>>(T1, elw, elb, srcEa, startA, cnt, scsh + 0, Ab);
    mm_mfma<128, 0, 64, 64><<<mm_grid, 256, 0, stream>>>(Ab, nullptr, Wb2, biasp + 128, T2, stats + 256, n);
    bn_finalize<64><<<1, 64, 0, stream>>>(stats + 256, c2g, c2bt, scsh + 256, inv_n);

    // ---- lin1: in = [t1|t2], BN affines folded into weights
    fold_w<<<96, 64, 0, stream>>>(l1w, l1b, scsh + 0, scsh + 256, Wb3, biasp + 256, 128, 64, 96);
    mm_mfma<128, 64, 96, 96><<<mm_grid, 256, 0, stream>>>(T1, T2, Wb3, biasp + 256, T3, stats + 512, n);
    bn_finalize<96><<<1, 96, 0, stream>>>(stats + 512, l1g, l1bt, scsh + 512, inv_n);

    // ---- mlp1 layer1
    fold_w<<<96, 64, 0, stream>>>(m1w, m1b, scsh + 512, nullptr, Wb4, biasp + 384, 96, 0, 96);
    mm_mfma<96, 0, 96, 96><<<mm_grid, 256, 0, stream>>>(T3, nullptr, Wb4, biasp + 384, T4, stats + 768, n);
    bn_finalize<96><<<1, 96, 0, stream>>>(stats + 768, m1g, m1bt, scsh + 768, inv_n);

    // ---- mlp1 layer2 (DOUT=8, padded to 16)
    fold_w<<<16, 64, 0, stream>>>(m2w, m2b, scsh + 768, nullptr, Wb5, biasp + 512, 96, 0, 8);
    mm_mfma<96, 0, 16, 8><<<mm_grid, 256, 0, stream>>>(T4, nullptr, Wb5, biasp + 512, T5, stats + 1024, n);
    bn_finalize<8><<<1, 8, 0, stream>>>(stats + 1024, m2g, m2bt, scsh + 1024, inv_n);
    bn_apply_out<<<(n * 8 + 255) / 256, 256, 0, stream>>>(T5, scsh + 1024, (float*)d_out, n * 8);
}

// Round 5
// 494.128 us; speedup vs baseline: 2.8880x; 1.0151x over previous
//
#include <hip/hip_runtime.h>

// ---------------------------------------------------------------------------
// GINENet, N=50000, E=800000, D=128.
// Round 5: wave-per-node aggregation with packed u32 lanes + 8-deep edge
// unroll (gather MLP); bn_finalize folded into fold_w / bn_apply_out.
// ---------------------------------------------------------------------------

typedef unsigned short u16;
typedef unsigned int u32;

using bfrag = __attribute__((ext_vector_type(8))) short;  // 8 bf16
using ffrag = __attribute__((ext_vector_type(4))) float;  // 4 fp32 acc

__device__ __forceinline__ u16 f2b(float f) {
    u32 u = __float_as_uint(f);
    return (u16)((u + 0x7FFFu + ((u >> 16) & 1u)) >> 16);   // RNE
}
__device__ __forceinline__ float b2f(u16 h) {
    return __uint_as_float(((u32)h) << 16);
}
__device__ __forceinline__ float b2f_lo(u32 g) { return __uint_as_float(g << 16); }
__device__ __forceinline__ float b2f_hi(u32 g) { return __uint_as_float(g & 0xffff0000u); }

#define BN_EPS 1e-5f

// ============================ CSR build =====================================
__global__ void histo(const int* __restrict__ ei, int* __restrict__ cnt, int E) {
    int i = blockIdx.x * blockDim.x + threadIdx.x;
    if (i < E) atomicAdd(&cnt[ei[E + i]], 1);
}

__global__ void scan_block(const int* __restrict__ cnt, int* __restrict__ excl,
                           int* __restrict__ part, int n) {
    __shared__ int s[256];
    int t = threadIdx.x;
    int base = blockIdx.x * 1024 + t * 4;
    int v0 = (base + 0 < n) ? cnt[base + 0] : 0;
    int v1 = (base + 1 < n) ? cnt[base + 1] : 0;
    int v2 = (base + 2 < n) ? cnt[base + 2] : 0;
    int v3 = (base + 3 < n) ? cnt[base + 3] : 0;
    int tsum = v0 + v1 + v2 + v3;
    s[t] = tsum;
    __syncthreads();
    for (int off = 1; off < 256; off <<= 1) {
        int x = (t >= off) ? s[t - off] : 0;
        __syncthreads();
        s[t] += x;
        __syncthreads();
    }
    int tbase = s[t] - tsum;
    if (base + 0 < n) excl[base + 0] = tbase;
    if (base + 1 < n) excl[base + 1] = tbase + v0;
    if (base + 2 < n) excl[base + 2] = tbase + v0 + v1;
    if (base + 3 < n) excl[base + 3] = tbase + v0 + v1 + v2;
    if (t == 255) part[blockIdx.x] = s[255];
}

__global__ void scan_carry(int* part, int nb) {
    int run = 0;
    for (int i = 0; i < nb; ++i) { int v = part[i]; part[i] = run; run += v; }
}

__global__ void scan_add(int* __restrict__ excl, const int* __restrict__ part, int n) {
    int i = blockIdx.x * blockDim.x + threadIdx.x;
    if (i < n) excl[i] += part[i >> 10];
}

__global__ void scatter_csr(const int* __restrict__ ei, const float* __restrict__ ea,
                            const int* __restrict__ start, int* __restrict__ fill,
                            int2* __restrict__ srcEa, int E) {
    int i = blockIdx.x * blockDim.x + threadIdx.x;
    if (i < E) {
        int dnode = ei[E + i];
        int pos = start[dnode] + atomicAdd(&fill[dnode], 1);
        srcEa[pos] = make_int2(ei[i], __float_as_int(ea[i]));
    }
}

// ======================== fp32 -> bf16 convert ==============================
__global__ void conv_f2b(const float4* __restrict__ src, uint2* __restrict__ dst, int n4) {
    int i = blockIdx.x * blockDim.x + threadIdx.x;
    if (i < n4) {
        float4 v = src[i];
        uint2 o;
        o.x = (u32)f2b(v.x) | ((u32)f2b(v.y) << 16);
        o.y = (u32)f2b(v.z) | ((u32)f2b(v.w) << 16);
        dst[i] = o;
    }
}

// ==================== weight fold (+BN finalize) + bf16 =====================
// in-feature k's BN affine computed from raw column stats (or identity when
// stats==nullptr): sc=g*rsqrt(var+eps), sh=beta-mu*sc.
// Wb[o][k] = bf16(W[o][k]*sc[k]); biasp[o] = bias[o] + sum_k W[o][k]*sh[k].
// Pad rows o>=DOUT zero-filled. One wave per output row.
__global__ __launch_bounds__(64)
void fold_w(const float* __restrict__ W, const float* __restrict__ bias,
            const float* __restrict__ stA, const float* __restrict__ gA,
            const float* __restrict__ btA, int DA,
            const float* __restrict__ stB, const float* __restrict__ gB,
            const float* __restrict__ btB, int DB,
            u16* __restrict__ Wb, float* __restrict__ biasp, int DOUT, float inv_n) {
    int o = blockIdx.x;
    int DIN = DA + DB;
    int lane = threadIdx.x;
    if (o >= DOUT) {
        for (int k = lane; k < DIN; k += 64) Wb[o * DIN + k] = 0;
        if (lane == 0) biasp[o] = 0.f;
        return;
    }
    float part = 0.f;
    for (int k = lane; k < DIN; k += 64) {
        float w = W[o * DIN + k];
        float sc = 1.f, sh = 0.f;
        if (k < DA) {
            if (stA) {
                float mu = stA[k] * inv_n;
                float var = stA[DA + k] * inv_n - mu * mu;
                sc = gA[k] * rsqrtf(var + BN_EPS);
                sh = fmaf(-mu, sc, btA[k]);
            }
        } else {
            int kb = k - DA;
            if (stB) {
                float mu = stB[kb] * inv_n;
                float var = stB[DB + kb] * inv_n - mu * mu;
                sc = gB[kb] * rsqrtf(var + BN_EPS);
                sh = fmaf(-mu, sc, btB[kb]);
            }
        }
        Wb[o * DIN + k] = f2b(w * sc);
        part += w * sh;
    }
    for (int off = 32; off; off >>= 1) part += __shfl_down(part, off);
    if (lane == 0) biasp[o] = bias[o] + part;
}

__global__ void bn_finalize128(const float* __restrict__ sums, const float* __restrict__ g,
                               const float* __restrict__ beta, float* __restrict__ scsh,
                               float inv_n) {
    int c = threadIdx.x;
    float mu = sums[c] * inv_n;
    float var = sums[128 + c] * inv_n - mu * mu;
    float sc = g[c] * rsqrtf(var + BN_EPS);
    scsh[c] = sc;
    scsh[128 + c] = fmaf(-mu, sc, beta[c]);
}

// =================== gather-side GINE aggregation ===========================
// One WAVE per node v; lane holds packed feature pair (2l, 2l+1) as u32.
// agg[v] = xbn[v] + sum_j relu(xbn[src_j] + ea_j*ew + eb),  xbn = x*sc+sh.
// 8-deep edge unroll -> 8 outstanding 256B gathers per wave.
__global__ __launch_bounds__(256)
void agg_csr(const u32* __restrict__ x2, const float* __restrict__ ew,
             const float* __restrict__ eb, const int2* __restrict__ srcEa,
             const int* __restrict__ start, const int* __restrict__ cnt,
             const float* __restrict__ scsh, u32* __restrict__ agg2, int n) {
    int v = blockIdx.x * 4 + (threadIdx.x >> 6);
    if (v >= n) return;
    int lane = threadIdx.x & 63;
    int s0 = start[v];
    int deg = cnt[v];
    float w0 = ew[2 * lane], w1 = ew[2 * lane + 1];
    float b0 = eb[2 * lane], b1 = eb[2 * lane + 1];
    float sc0 = 1.f, sh0 = 0.f, sc1 = 1.f, sh1 = 0.f;
    if (scsh) {
        sc0 = scsh[2 * lane];     sh0 = scsh[128 + 2 * lane];
        sc1 = scsh[2 * lane + 1]; sh1 = scsh[129 + 2 * lane];
    }
    float a0 = 0.f, a1 = 0.f;
    int j = 0;
    for (; j + 7 < deg; j += 8) {
        int2 p[8];
        u32 g[8];
#pragma unroll
        for (int t = 0; t < 8; ++t) p[t] = srcEa[s0 + j + t];
#pragma unroll
        for (int t = 0; t < 8; ++t) g[t] = x2[(long)p[t].x * 64 + lane];
#pragma unroll
        for (int t = 0; t < 8; ++t) {
            float eav = __int_as_float(p[t].y);
            float e0 = fmaf(eav, w0, b0);
            float e1 = fmaf(eav, w1, b1);
            a0 += fmaxf(fmaf(b2f_lo(g[t]), sc0, sh0) + e0, 0.f);
            a1 += fmaxf(fmaf(b2f_hi(g[t]), sc1, sh1) + e1, 0.f);
        }
    }
    for (; j < deg; ++j) {
        int2 p = srcEa[s0 + j];
        u32 g = x2[(long)p.x * 64 + lane];
        float eav = __int_as_float(p.y);
        a0 += fmaxf(fmaf(b2f_lo(g), sc0, sh0) + fmaf(eav, w0, b0), 0.f);
        a1 += fmaxf(fmaf(b2f_hi(g), sc1, sh1) + fmaf(eav, w1, b1), 0.f);
    }
    u32 gs = x2[(long)v * 64 + lane];
    float r0 = fmaf(b2f_lo(gs), sc0, sh0) + a0;
    float r1 = fmaf(b2f_hi(gs), sc1, sh1) + a1;
    agg2[(long)v * 64 + lane] = (u32)f2b(r0) | ((u32)f2b(r1) << 16);
}

// ======================= MFMA matmul + relu + stats =========================
template <int DIN0, int DIN1, int DOUTP, int DOUT>
__global__ __launch_bounds__(256)
void mm_mfma(const u16* __restrict__ in0, const u16* __restrict__ in1,
             const u16* __restrict__ Wb, const float* __restrict__ biasp,
             u16* __restrict__ out, float* __restrict__ stats, int n) {
    constexpr int DIN = DIN0 + DIN1;
    constexpr int DINP = DIN + 8;
    constexpr int BM = 64;
    constexpr int NCF = DOUTP / 16;   // col fragments
    constexpr int NKT = DIN / 32;     // k tiles
    __shared__ u16 yS[BM * DINP];
    __shared__ u16 wS[DOUTP * DINP];
    const int tid = threadIdx.x;
    const int row0 = blockIdx.x * BM;

    for (int idx = tid; idx < DOUTP * (DIN / 8); idx += 256) {
        int o = idx / (DIN / 8), c = idx % (DIN / 8);
        uint4 v = *(const uint4*)(Wb + (long)o * DIN + c * 8);
        *(uint4*)&wS[o * DINP + c * 8] = v;
    }
    for (int idx = tid; idx < BM * (DIN0 / 8); idx += 256) {
        int r = idx / (DIN0 / 8), c = idx % (DIN0 / 8);
        int gr = row0 + r;
        uint4 v = make_uint4(0, 0, 0, 0);
        if (gr < n) v = *(const uint4*)(in0 + (long)gr * DIN0 + c * 8);
        *(uint4*)&yS[r * DINP + c * 8] = v;
    }
    if (DIN1 > 0) {
        for (int idx = tid; idx < BM * (DIN1 / 8); idx += 256) {
            int r = idx / (DIN1 / 8), c = idx % (DIN1 / 8);
            int gr = row0 + r;
            uint4 v = make_uint4(0, 0, 0, 0);
            if (gr < n) v = *(const uint4*)(in1 + (long)gr * DIN1 + c * 8);
            *(uint4*)&yS[r * DINP + DIN0 + c * 8] = v;
        }
    }
    __syncthreads();

    const int wv = tid >> 6;
    const int lane = tid & 63;
    const int mrow = lane & 15;
    const int kg = lane >> 4;

    ffrag acc[NCF];
#pragma unroll
    for (int cf = 0; cf < NCF; ++cf) acc[cf] = (ffrag){0.f, 0.f, 0.f, 0.f};

    const u16* yBase = &yS[(wv * 16 + mrow) * DINP + kg * 8];
#pragma unroll
    for (int kt = 0; kt < NKT; ++kt) {
        bfrag a = *(const bfrag*)(yBase + kt * 32);
#pragma unroll
        for (int cf = 0; cf < NCF; ++cf) {
            bfrag b = *(const bfrag*)&wS[(cf * 16 + mrow) * DINP + kt * 32 + kg * 8];
            acc[cf] = __builtin_amdgcn_mfma_f32_16x16x32_bf16(a, b, acc[cf], 0, 0, 0);
        }
    }

    __syncthreads();
    float* cs = (float*)yS;
    for (int i = tid; i < 2 * DOUT; i += 256) cs[i] = 0.f;
    __syncthreads();

    const int col = lane & 15;
#pragma unroll
    for (int cf = 0; cf < NCF; ++cf) {
        int c = cf * 16 + col;
        if (DOUTP != DOUT && c >= DOUT) continue;
        float bv = biasp[c];
        float bsum = 0.f, bss = 0.f;
#pragma unroll
        for (int r = 0; r < 4; ++r) {
            int gr = row0 + wv * 16 + kg * 4 + r;
            if (gr < n) {
                float v = fmaxf(acc[cf][r] + bv, 0.f);
                out[(long)gr * DOUT + c] = f2b(v);
                bsum += v;
                bss += v * v;
            }
        }
        atomicAdd(&cs[c], bsum);
        atomicAdd(&cs[DOUT + c], bss);
    }
    __syncthreads();
    for (int i = tid; i < 2 * DOUT; i += 256) atomicAdd(&stats[i], cs[i]);
}

// ===================== final BN (stats -> output) ===========================
__global__ void bn_apply_out(const u16* __restrict__ t, const float* __restrict__ stats,
                             const float* __restrict__ g, const float* __restrict__ beta,
                             float* __restrict__ out, int total, float inv_n) {
    int i = blockIdx.x * blockDim.x + threadIdx.x;
    if (i < total) {
        int c = i & 7;
        float mu = stats[c] * inv_n;
        float var = stats[8 + c] * inv_n - mu * mu;
        float sc = g[c] * rsqrtf(var + BN_EPS);
        out[i] = fmaf(b2f(t[i]) - mu, sc, beta[c]);
    }
}

// ============================ driver ========================================
extern "C" void kernel_launch(void* const* d_in, const int* in_sizes, int n_in,
                              void* d_out, int out_size, void* d_ws, size_t ws_size,
                              hipStream_t stream) {
    const float* x    = (const float*)d_in[0];
    const int*   ei   = (const int*)d_in[1];
    const float* ea   = (const float*)d_in[2];
    const float* elw  = (const float*)d_in[3];
    const float* elb  = (const float*)d_in[4];
    const float* c1w  = (const float*)d_in[5];
    const float* c1b  = (const float*)d_in[6];
    const float* c1g  = (const float*)d_in[7];
    const float* c1bt = (const float*)d_in[8];
    const float* c2w  = (const float*)d_in[9];
    const float* c2b  = (const float*)d_in[10];
    const float* c2g  = (const float*)d_in[11];
    const float* c2bt = (const float*)d_in[12];
    const float* l1w  = (const float*)d_in[13];
    const float* l1b  = (const float*)d_in[14];
    const float* l1g  = (const float*)d_in[15];
    const float* l1bt = (const float*)d_in[16];
    const float* m1w  = (const float*)d_in[17];
    const float* m1b  = (const float*)d_in[18];
    const float* m1g  = (const float*)d_in[19];
    const float* m1bt = (const float*)d_in[20];
    const float* m2w  = (const float*)d_in[21];
    const float* m2b  = (const float*)d_in[22];
    const float* m2g  = (const float*)d_in[23];
    const float* m2bt = (const float*)d_in[24];

    const int n = in_sizes[0] / 128;   // 50000
    const int E = in_sizes[2];         // 800000
    const float inv_n = 1.0f / (float)n;

    char* wp = (char*)d_ws;
    auto alloc = [&](size_t bytes) { char* p = wp; wp += (bytes + 31) & ~(size_t)31; return p; };

    float* stats  = (float*)alloc(1280 * 4);
    float* scsh0  = (float*)alloc(256 * 4);
    float* biasp  = (float*)alloc(5 * 128 * 4);
    int*   cnt    = (int*)alloc((size_t)n * 4);
    int*   fill   = (int*)alloc((size_t)n * 4);     // contiguous after cnt
    int*   startA = (int*)alloc((size_t)n * 4);
    int*   part   = (int*)alloc(64 * 4);
    int2*  srcEa  = (int2*)alloc((size_t)E * 8);
    u16*   xb     = (u16*)alloc((size_t)n * 128 * 2);
    u16*   Ab     = (u16*)alloc((size_t)n * 128 * 2);
    u16*   T1     = (u16*)alloc((size_t)n * 128 * 2);
    u16*   T2     = (u16*)alloc((size_t)n * 64 * 2);
    u16*   T3     = (u16*)alloc((size_t)n * 96 * 2);
    u16*   T4     = (u16*)alloc((size_t)n * 96 * 2);
    u16*   T5     = (u16*)alloc((size_t)n * 8 * 2);
    u16*   Wb1    = (u16*)alloc(128 * 128 * 2);
    u16*   Wb2    = (u16*)alloc(64 * 128 * 2);
    u16*   Wb3    = (u16*)alloc(96 * 192 * 2);
    u16*   Wb4    = (u16*)alloc(96 * 96 * 2);
    u16*   Wb5    = (u16*)alloc(16 * 96 * 2);

    hipMemsetAsync(stats, 0, 1280 * 4, stream);
    hipMemsetAsync(cnt, 0, (size_t)2 * n * 4, stream);   // cnt + fill

    const int eg_grid = (E + 255) / 256;
    const int mm_grid = (n + 63) / 64;
    const int ag_grid = (n + 3) / 4;
    const int nb = (n + 1023) / 1024;

    // ---- CSR build (dst-sorted, edge attr folded into payload)
    histo<<<eg_grid, 256, 0, stream>>>(ei, cnt, E);
    scan_block<<<nb, 256, 0, stream>>>(cnt, startA, part, n);
    scan_carry<<<1, 1, 0, stream>>>(part, nb);
    scan_add<<<(n + 255) / 256, 256, 0, stream>>>(startA, part, n);
    scatter_csr<<<eg_grid, 256, 0, stream>>>(ei, ea, startA, fill, srcEa, E);

    // ---- input conversion + identity weight folds
    conv_f2b<<<(n * 32 + 255) / 256, 256, 0, stream>>>((const float4*)x, (uint2*)xb, n * 32);
    fold_w<<<128, 64, 0, stream>>>(c1w, c1b, nullptr, nullptr, nullptr, 128,
                                   nullptr, nullptr, nullptr, 0, Wb1, biasp + 0, 128, inv_n);
    fold_w<<<64, 64, 0, stream>>>(c2w, c2b, nullptr, nullptr, nullptr, 128,
                                  nullptr, nullptr, nullptr, 0, Wb2, biasp + 128, 64, inv_n);

    // ---- conv1
    agg_csr<<<ag_grid, 256, 0, stream>>>((const u32*)xb, elw, elb, srcEa, startA, cnt,
                                         nullptr, (u32*)Ab, n);
    mm_mfma<128, 0, 128, 128><<<mm_grid, 256, 0, stream>>>(Ab, nullptr, Wb1, biasp + 0, T1, stats + 0, n);
    bn_finalize128<<<1, 128, 0, stream>>>(stats + 0, c1g, c1bt, scsh0, inv_n);

    // ---- conv2 (BN(t1) applied inside the gather)
    agg_csr<<<ag_grid, 256, 0, stream>>>((const u32*)T1, elw, elb, srcEa, startA, cnt,
                                         scsh0, (u32*)Ab, n);
    mm_mfma<128, 0, 64, 64><<<mm_grid, 256, 0, stream>>>(Ab, nullptr, Wb2, biasp + 128, T2, stats + 256, n);

    // ---- lin1: in = [t1|t2], both BN affines folded into weights from stats
    fold_w<<<96, 64, 0, stream>>>(l1w, l1b, stats + 0, c1g, c1bt, 128,
                                  stats + 256, c2g, c2bt, 64, Wb3, biasp + 256, 96, inv_n);
    mm_mfma<128, 64, 96, 96><<<mm_grid, 256, 0, stream>>>(T1, T2, Wb3, biasp + 256, T3, stats + 512, n);

    // ---- mlp1 layer1
    fold_w<<<96, 64, 0, stream>>>(m1w, m1b, stats + 512, l1g, l1bt, 96,
                                  nullptr, nullptr, nullptr, 0, Wb4, biasp + 384, 96, inv_n);
    mm_mfma<96, 0, 96, 96><<<mm_grid, 256, 0, stream>>>(T3, nullptr, Wb4, biasp + 384, T4, stats + 768, n);

    // ---- mlp1 layer2 (DOUT=8 padded to 16)
    fold_w<<<16, 64, 0, stream>>>(m2w, m2b, stats + 768, m1g, m1bt, 96,
                                  nullptr, nullptr, nullptr, 0, Wb5, biasp + 512, 8, inv_n);
    mm_mfma<96, 0, 16, 8><<<mm_grid, 256, 0, stream>>>(T4, nullptr, Wb5, biasp + 512, T5, stats + 1024, n);
    bn_apply_out<<<(n * 8 + 255) / 256, 256, 0, stream>>>(T5, stats + 1024, m2g, m2bt,
                                                          (float*)d_out, n * 8, inv_n);
}